// Round 15
// baseline (171.338 us; speedup 1.0000x reference)
//
#include <hip/hip_runtime.h>

// MultiHeadAttn fused pipeline for MI355X (gfx950).
// B=2, S=2048, D=1024, H=16, HD=64. Round 15:
//  - f32->bf16 conversion of q/k/v fused into QKV-GEMM A-staging (reg-stage:
//    load f32 early, cvt_pk+ds_write after compute). cvt_bf16_3 eliminated.
//  - transpose_cvt_w4 + cvt_mask_bits merged into one launch (prep_wm).
//  - attn / Wo-GEMM / LN identical to round 14.

#define NB 2
#define SS 2048
#define DDIM 1024
#define NH 16
#define HDIM 64
#define MROWS (NB * SS)  // 4096

typedef unsigned short u16;
typedef unsigned long long u64;
typedef unsigned int u32;
typedef short bf16x8 __attribute__((ext_vector_type(8)));
typedef float f32x4 __attribute__((ext_vector_type(4)));

typedef const __attribute__((address_space(1))) void GASV;
typedef __attribute__((address_space(3))) void LASV;

__device__ __forceinline__ float dev_exp2(float x) {
  float r;
  asm("v_exp_f32 %0, %1" : "=v"(r) : "v"(x));
  return r;
}

__device__ __forceinline__ u16 f2bf(float f) {
  unsigned u = __builtin_bit_cast(unsigned, f);
  u += 0x7FFFu + ((u >> 16) & 1u);  // RNE; inputs finite
  return (u16)(u >> 16);
}

__device__ __forceinline__ u32 cvt_pk_bf16(float a, float b) {
  u32 d;  // D[15:0]=bf16(a), D[31:16]=bf16(b)  (RNE, matches f2bf)
  asm("v_cvt_pk_bf16_f32 %0, %1, %2" : "=v"(d) : "v"(a), "v"(b));
  return d;
}

// ------- merged prep: W transpose-cvt (blocks 0..1023) + mask bitpack -------
__global__ __launch_bounds__(256) void prep_wm(const float* __restrict__ W0,
                                               const float* __restrict__ W1,
                                               const float* __restrict__ W2,
                                               const float* __restrict__ W3,
                                               u16* __restrict__ WTbase,
                                               const int* __restrict__ maskin,
                                               u64* __restrict__ mbits) {
  const int bid = blockIdx.x, tid = threadIdx.x;
  if (bid < 1024) {
    __shared__ u16 t[64][65];
    const int z = bid >> 8;
    const float* W = (z == 0) ? W0 : (z == 1) ? W1 : (z == 2) ? W2 : W3;
    u16* WT = WTbase + (size_t)z * DDIM * DDIM;
    const int k0 = ((bid >> 4) & 15) * 64, n0 = (bid & 15) * 64;
    const int r = tid >> 4;          // 0..15
    const int c4 = (tid & 15) * 4;   // col group
#pragma unroll
    for (int it = 0; it < 4; ++it) {
      int k = r + it * 16;
      float4 v = *(const float4*)&W[(size_t)(k0 + k) * DDIM + n0 + c4];
      t[c4 + 0][k] = f2bf(v.x);
      t[c4 + 1][k] = f2bf(v.y);
      t[c4 + 2][k] = f2bf(v.z);
      t[c4 + 3][k] = f2bf(v.w);
    }
    __syncthreads();
#pragma unroll
    for (int it = 0; it < 4; ++it) {
      int n = r + it * 16;
      uint2 o;
      u16* po = (u16*)&o;
#pragma unroll
      for (int j = 0; j < 4; ++j) po[j] = t[n][c4 + j];
      *(uint2*)&WT[(size_t)(n0 + n) * DDIM + k0 + c4] = o;
    }
  } else {
    size_t w = ((size_t)(bid - 1024) * 256 + tid) >> 6;
    int lane = tid & 63;
    int v = maskin[w * 64 + lane];
    u64 bits = __ballot(v != 0);  // bit l = (mask[w*64+l] != 0)
    if (lane == 0) mbits[w] = bits;
  }
}

// ---------------- GEMM: 128x128 tile, BK=64, 2-phase double-buffer ----------
// MODE 0: fused QKV with on-the-fly f32->bf16 A conversion (reg-staged A,
//         gload_lds B). sel = colB0>>10: 0->Qp (scaled 0.125*log2e), 1->Kp,
//         2->V transposed via LDS restage, coalesced write to VpT[bh][d][s].
// MODE 1: Wo proj (bf16 A via gload_lds), f32 out = acc + b0 + resid.
// Col-fast XCD swizzle: each XCD owns 4 row-panels x all col-panels.
template <int MODE>
__global__ __launch_bounds__(256) void gemm_bt(const float* __restrict__ Af0,
                                               const float* __restrict__ Af1,
                                               const float* __restrict__ Af2,
                                               const u16* __restrict__ Abf,
                                               const u16* __restrict__ BT,
                                               const float* __restrict__ b0,
                                               const float* __restrict__ b1,
                                               const float* __restrict__ b2,
                                               const float* __restrict__ resid,
                                               void* __restrict__ C,
                                               void* __restrict__ Cv) {
  __shared__ __align__(16) u16 SMEM[2][2][128][64];  // [0]=A tiles, [1]=B tiles
  u16(&Al)[2][128][64] = SMEM[0];
  u16(&Bl)[2][128][64] = SMEM[1];
  const int tid = threadIdx.x;
  const int wid = tid >> 6, lane = tid & 63;
  const int wm = (wid >> 1) * 64, wn = (wid & 1) * 64;
  const int NCOL = (MODE == 0) ? 24 : 8;
  const int lin = blockIdx.y * 32 + blockIdx.x;
  const int xcd = lin & 7, idx = lin >> 3;
  const int rowA0 = (xcd * 4 + idx / NCOL) * 128;
  const int colB0 = (idx % NCOL) * 128;
  const int sel = (MODE == 0) ? (colB0 >> 10) : 0;
  const float* Af = nullptr;
  const u16* Ag = nullptr;
  if (MODE == 0) {
    Af = ((sel == 0) ? Af0 : (sel == 1) ? Af1 : Af2) + (size_t)rowA0 * DDIM;
  } else {
    Ag = Abf + (size_t)rowA0 * DDIM;
  }
  const u16* Bg = BT + (size_t)colB0 * DDIM;
  f32x4 acc[4][4] = {};
  const int rl = lane >> 3;        // 0..7
  const int ce = (lane & 7) * 8;   // chunk offset (elems)

  float4 pa0[4], pa1[4];  // MODE0: in-flight f32 A chunks (32B/lane, coalesced)

#define A_LOADF(kt)                                                            \
  do {                                                                         \
    _Pragma("unroll") for (int c = 0; c < 4; ++c) {                            \
      int row = wid * 32 + c * 8 + rl;                                         \
      pa0[c] = *(const float4*)(Af + (size_t)row * DDIM + (kt) + ce);          \
      pa1[c] = *(const float4*)(Af + (size_t)row * DDIM + (kt) + ce + 4);      \
    }                                                                          \
  } while (0)

#define A_WRITEF(buf)                                                          \
  do {                                                                         \
    _Pragma("unroll") for (int c = 0; c < 4; ++c) {                            \
      int row = wid * 32 + c * 8 + rl;                                         \
      bf16x8 w;                                                                \
      u32* pw32 = (u32*)&w;                                                    \
      pw32[0] = cvt_pk_bf16(pa0[c].x, pa0[c].y);                               \
      pw32[1] = cvt_pk_bf16(pa0[c].z, pa0[c].w);                               \
      pw32[2] = cvt_pk_bf16(pa1[c].x, pa1[c].y);                               \
      pw32[3] = cvt_pk_bf16(pa1[c].z, pa1[c].w);                               \
      *(bf16x8*)&Al[buf][row][ce] = w;                                         \
    }                                                                          \
  } while (0)

#define A_GLOAD(buf, kt)                                                       \
  do {                                                                         \
    _Pragma("unroll") for (int c = 0; c < 4; ++c) {                            \
      int rt = wid * 32 + c * 8;                                               \
      __builtin_amdgcn_global_load_lds(                                        \
          (GASV*)(Ag + (size_t)(rt + rl) * DDIM + (kt) + ce),                  \
          (LASV*)((char*)&Al[buf][0][0] + rt * 128), 16, 0, 0);                \
    }                                                                          \
  } while (0)

#define B_STAGE(buf, kt)                                                       \
  do {                                                                         \
    _Pragma("unroll") for (int c = 0; c < 4; ++c) {                            \
      int rt = wid * 32 + c * 8;                                               \
      __builtin_amdgcn_global_load_lds(                                        \
          (GASV*)(Bg + (size_t)(rt + rl) * DDIM + (kt) + ce),                  \
          (LASV*)((char*)&Bl[buf][0][0] + rt * 128), 16, 0, 0);                \
    }                                                                          \
  } while (0)

  // prologue: tile 0
  if (MODE == 0) {
    A_LOADF(0);
    B_STAGE(0, 0);
    A_WRITEF(0);  // compiler inserts vmcnt wait for pa loads
  } else {
    A_GLOAD(0, 0);
    B_STAGE(0, 0);
  }
  __syncthreads();
  for (int t = 0; t < 16; ++t) {  // K = 1024 = 16 * 64
    const int cur = t & 1;
    if (t < 15) {
      if (MODE == 0) A_LOADF((t + 1) * 64);  // issue early (T14 split)
      else A_GLOAD(cur ^ 1, (t + 1) * 64);
      B_STAGE(cur ^ 1, (t + 1) * 64);
    }
#pragma unroll
    for (int kk = 0; kk < 64; kk += 32) {
      bf16x8 af[4], bfr[4];
#pragma unroll
      for (int i = 0; i < 4; ++i)
        af[i] = *(const bf16x8*)&Al[cur][wm + i * 16 + (lane & 15)][kk + (lane >> 4) * 8];
#pragma unroll
      for (int j = 0; j < 4; ++j)
        bfr[j] = *(const bf16x8*)&Bl[cur][wn + j * 16 + (lane & 15)][kk + (lane >> 4) * 8];
#pragma unroll
      for (int i = 0; i < 4; ++i)
#pragma unroll
        for (int j = 0; j < 4; ++j)
          acc[i][j] = __builtin_amdgcn_mfma_f32_16x16x32_bf16(af[i], bfr[j], acc[i][j], 0, 0, 0);
    }
    if (MODE == 0 && t < 15) A_WRITEF(cur ^ 1);  // write-late: loads hidden
    __syncthreads();
  }
#undef A_LOADF
#undef A_WRITEF
#undef A_GLOAD
#undef B_STAGE

  const int cb = lane & 15, hi = lane >> 4;
  if (MODE == 0) {
    if (sel == 2) {
      // V: restage transposed in LDS, then coalesced 16B/lane writes.
      u16(*T)[136] = (u16(*)[136]) & SMEM[0][0][0][0];  // 128x136 u16 = 34.8KB
      const int dcol0 = colB0 & 1023;
#pragma unroll
      for (int j = 0; j < 4; ++j) {
        int dl = wn + j * 16 + cb;  // local d 0..127
        float bv = b2[dcol0 + dl];
#pragma unroll
        for (int i = 0; i < 4; ++i) {
          int sl = wm + i * 16 + hi * 4;  // local s, 4 consecutive
          uint2 o;
          o.x = cvt_pk_bf16(acc[i][j][0] + bv, acc[i][j][1] + bv);
          o.y = cvt_pk_bf16(acc[i][j][2] + bv, acc[i][j][3] + bv);
          *(uint2*)&T[dl][sl] = o;
        }
      }
      __syncthreads();
      const int bb = rowA0 >> 11, s0 = rowA0 & (SS - 1);
#pragma unroll
      for (int it = 0; it < 8; ++it) {
        int chunk = it * 256 + tid;     // 0..2047
        int dl = chunk >> 4;            // 0..127
        int sc = (chunk & 15) * 8;      // u16 offset within row
        int dg = dcol0 + dl;
        *(bf16x8*)&((u16*)Cv)[((size_t)(bb * NH + (dg >> 6)) * HDIM + (dg & 63)) * SS +
                              s0 + sc] = *(const bf16x8*)&T[dl][sc];
      }
    } else {
      const float* bp = (sel == 0) ? b0 : b1;
      const float scale = (sel == 0) ? 0.125f * 1.44269504088896340736f : 1.0f;
      u16* dst = (u16*)C + (size_t)sel * ((size_t)MROWS * DDIM);
      const int colw0 = (colB0 & 1023) + wn;
#pragma unroll
      for (int i = 0; i < 4; ++i)
#pragma unroll
        for (int j = 0; j < 4; ++j) {
          int colw = colw0 + j * 16 + cb;
          float bv = bp[colw];
#pragma unroll
          for (int r = 0; r < 4; ++r) {
            int row = rowA0 + wm + i * 16 + hi * 4 + r;
            dst[(size_t)row * DDIM + colw] = f2bf((acc[i][j][r] + bv) * scale);
          }
        }
    }
  } else {
#pragma unroll
    for (int i = 0; i < 4; ++i)
#pragma unroll
      for (int j = 0; j < 4; ++j) {
        int col = colB0 + wn + j * 16 + cb;
        float bv = b0[col];
#pragma unroll
        for (int r = 0; r < 4; ++r) {
          int row = rowA0 + wm + i * 16 + hi * 4 + r;
          size_t off = (size_t)row * DDIM + col;
          ((float*)C)[off] = acc[i][j][r] + bv + resid[off];  // residual fused
        }
      }
  }
}

// ---------------- Flash attention (swapped QK^T, fixed-base softmax) --------
// grid: 512 blocks (XCD-swizzled). 8 waves; wave w owns q-rows [w*16,w*16+16)
// of a 128-row q-tile. Fixed m=0; masked -> exact 0 by underflow.
// 3-buffer K/V, ONE barrier/iter, counted vmcnt(2) (never drains prefetch).
__global__ __launch_bounds__(512, 4) void attn_fwd(const u16* __restrict__ Qp,
                                                   const u16* __restrict__ Kp,
                                                   const u16* __restrict__ VpT,
                                                   const u64* __restrict__ Mbits,
                                                   u16* __restrict__ O) {
  __shared__ __align__(16) u16 Kl[3][64][64];  // [buf][kv][d], swizzled
  __shared__ __align__(16) u16 Vl[3][64][64];  // [buf][d][kv], swizzled
  __shared__ __align__(16) u16 Pl[8][16][64];  // per-wave P [q][kv], swizzled
  const int tid = threadIdx.x, wid = tid >> 6, lane = tid & 63;
  const int bid = blockIdx.x;
  const int bh = (bid & 7) * 4 + ((bid >> 3) & 3);
  const int q0 = (bid >> 5) * 128;
  const int b = bh >> 4, h = bh & 15;
  const int hi = lane >> 4, cbase = lane & 15, lx = lane & 7;

  bf16x8 qf[2];
  {
    const u16* qb = Qp + (size_t)(b * SS + q0 + wid * 16 + cbase) * DDIM + h * 64 + hi * 8;
    qf[0] = *(const bf16x8*)qb;
    qf[1] = *(const bf16x8*)(qb + 32);
  }
  const bf16x8 ONES8 = {(short)0x3F80, (short)0x3F80, (short)0x3F80, (short)0x3F80,
                        (short)0x3F80, (short)0x3F80, (short)0x3F80, (short)0x3F80};
  f32x4 l_acc = (f32x4){0.f, 0.f, 0.f, 0.f};
  f32x4 accO[4];
#pragma unroll
  for (int f = 0; f < 4; ++f) accO[f] = (f32x4){0.f, 0.f, 0.f, 0.f};

  const u16* Kgb = Kp + (size_t)b * SS * DDIM + h * 64;
  const u16* Vgb = VpT + (size_t)bh * 64 * SS;
  const u64* Mb = Mbits + (size_t)(b * SS + q0 + wid * 16 + cbase) * (SS / 64);
  const int rl = lane >> 3;
  const int ceS = ((lane & 7) ^ rl) * 8;  // pre-swizzled source chunk

  // hoisted LDS fragment offsets (u16 units within one 64x64 tile)
  int fo[4][2];
#pragma unroll
  for (int f = 0; f < 4; ++f)
#pragma unroll
    for (int ks = 0; ks < 2; ++ks)
      fo[f][ks] = (f * 16 + cbase) * 64 + (((ks * 4 + hi) ^ lx) << 3);
  int pw[4];
#pragma unroll
  for (int f = 0; f < 4; ++f)
    pw[f] = cbase * 64 + (((f * 2 + (hi >> 1)) ^ lx) << 3) + ((hi & 1) << 2);
  u16* KlF = &Kl[0][0][0];
  u16* VlF = &Vl[0][0][0];
  u16* Plw = &Pl[wid][0][0];

  // 8 waves: each wave stages 8 rows of K and 8 rows of V (2 gloads/wave)
#define STAGE_KV(BUF, kv)                                                      \
  do {                                                                         \
    int rt = wid * 8;                                                          \
    __builtin_amdgcn_global_load_lds(                                          \
        (GASV*)(Kgb + (size_t)((kv) + rt + rl) * DDIM + ceS),                  \
        (LASV*)((char*)KlF + (BUF) * 8192 + rt * 128), 16, 0, 0);              \
    __builtin_amdgcn_global_load_lds(                                          \
        (GASV*)(Vgb + (size_t)(rt + rl) * SS + (kv) + ceS),                    \
        (LASV*)((char*)VlF + (BUF) * 8192 + rt * 128), 16, 0, 0);              \
  } while (0)

#define WAITVM(N) asm volatile("s_waitcnt vmcnt(" #N ")" ::: "memory")

// One iteration: counted-vmcnt wait + single barrier + prefetch t+2 + compute.
#define ATTN_ITER(T, BUF, DO_STAGE, VM)                                        \
  do {                                                                         \
    WAITVM(VM);                                                                \
    __builtin_amdgcn_s_barrier();                                              \
    u64 mrow = Mb[T];                                                          \
    if (DO_STAGE) STAGE_KV(((BUF) + 2) % 3, ((T) + 2) * 64);                   \
    f32x4 sc[4];                                                               \
    __builtin_amdgcn_s_setprio(1);                                             \
    _Pragma("unroll") for (int fn = 0; fn < 4; ++fn) {                         \
      f32x4 c = (f32x4){0.f, 0.f, 0.f, 0.f};                                   \
      _Pragma("unroll") for (int ks = 0; ks < 2; ++ks) {                       \
        bf16x8 kf = *(const bf16x8*)(KlF + (BUF) * 4096 + fo[fn][ks]);         \
        c = __builtin_amdgcn_mfma_f32_16x16x32_bf16(kf, qf[ks], c, 0, 0, 0);   \
      }                                                                        \
      sc[fn] = c;                                                              \
    }                                                                          \
    __builtin_amdgcn_s_setprio(0);                                             \
    /* p = exp2(s - 512*maskbit), fixed base m=0; masked -> exact 0 */         \
    u64 mh = mrow >> (hi * 4);                                                 \
    u32 mlo = (u32)mh, mhi2 = (u32)(mh >> 32);                                 \
    _Pragma("unroll") for (int fn = 0; fn < 4; ++fn) {                         \
      u32 b4 = ((fn < 2) ? mlo : mhi2) >> ((fn & 1) * 16);                     \
      _Pragma("unroll") for (int j = 0; j < 4; ++j) {                          \
        float bf_ = (float)((b4 >> j) & 1u);                                   \
        sc[fn][j] = dev_exp2(fmaf(bf_, -512.f, sc[fn][j]));                    \
      }                                                                        \
    }                                                                          \
    _Pragma("unroll") for (int fn = 0; fn < 4; ++fn) {                         \
      uint2 wpair;                                                             \
      wpair.x = cvt_pk_bf16(sc[fn][0], sc[fn][1]);                             \
      wpair.y = cvt_pk_bf16(sc[fn][2], sc[fn][3]);                             \
      *(uint2*)(Plw + pw[fn]) = wpair;                                         \
    }                                                                          \
    bf16x8 pf0 = *(const bf16x8*)(Plw + fo[0][0]);                             \
    bf16x8 pf1 = *(const bf16x8*)(Plw + fo[0][1]);                             \
    __builtin_amdgcn_s_setprio(1);                                             \
    l_acc = __builtin_amdgcn_mfma_f32_16x16x32_bf16(pf0, ONES8, l_acc, 0, 0, 0); \
    l_acc = __builtin_amdgcn_mfma_f32_16x16x32_bf16(pf1, ONES8, l_acc, 0, 0, 0); \
    _Pragma("unroll") for (int nd = 0; nd < 4; ++nd) {                         \
      bf16x8 v0 = *(const bf16x8*)(VlF + (BUF) * 4096 + fo[nd][0]);            \
      bf16x8 v1 = *(const bf16x8*)(VlF + (BUF) * 4096 + fo[nd][1]);            \
      accO[nd] = __builtin_amdgcn_mfma_f32_16x16x32_bf16(pf0, v0, accO[nd], 0, 0, 0); \
      accO[nd] = __builtin_amdgcn_mfma_f32_16x16x32_bf16(pf1, v1, accO[nd], 0, 0, 0); \
    }                                                                          \
    __builtin_amdgcn_s_setprio(0);                                             \
  } while (0)

  // prologue: two tiles in flight
  STAGE_KV(0, 0);
  STAGE_KV(1, 64);
  // main loop: 30 iters in x3 unroll (compile-time buffer index), vmcnt(2)
  for (int t3 = 0; t3 < 30; t3 += 3) {
    ATTN_ITER(t3 + 0, 0, true, 2);
    ATTN_ITER(t3 + 1, 1, true, 2);
    ATTN_ITER(t3 + 2, 2, true, 2);
  }
  // tail: t=30 (buf 0, no stage), t=31 (buf 1, full drain)
  ATTN_ITER(30, 0, false, 2);
  ATTN_ITER(31, 1, false, 0);
#undef ATTN_ITER
#undef WAITVM
#undef STAGE_KV

  // l_acc[j] = sum_kv P[q=hi*4+j][kv] (all columns of the ones-MFMA equal)
#pragma unroll
  for (int nd = 0; nd < 4; ++nd)
#pragma unroll
    for (int j = 0; j < 4; ++j) {
      int row = q0 + wid * 16 + hi * 4 + j;
      int col = h * 64 + nd * 16 + cbase;
      O[(size_t)(b * SS + row) * DDIM + col] = f2bf(accO[nd][j] / l_acc[j]);
    }
}

// ---------------- LayerNorm on x (residual already added) -------------------
// wave-per-row: 4 rows/block, pure shfl reduction, no LDS/barriers.
__global__ __launch_bounds__(256) void ln_res(const float* __restrict__ xin,
                                              const float* __restrict__ gamma,
                                              const float* __restrict__ beta,
                                              float* __restrict__ out) {
  const int tid = threadIdx.x, wid = tid >> 6, lane = tid & 63;
  const int row = blockIdx.x * 4 + wid;
  const float* xr = xin + (size_t)row * DDIM;
  float4 x[4];
  float s = 0.f;
#pragma unroll
  for (int i = 0; i < 4; ++i) {
    x[i] = *(const float4*)(xr + lane * 4 + i * 256);
    s += (x[i].x + x[i].y) + (x[i].z + x[i].w);
  }
#pragma unroll
  for (int off = 32; off >= 1; off >>= 1) s += __shfl_xor(s, off, 64);
  float mean = s * (1.0f / DDIM);
  float ss = 0.f;
#pragma unroll
  for (int i = 0; i < 4; ++i) {
    x[i].x -= mean; x[i].y -= mean; x[i].z -= mean; x[i].w -= mean;
    ss += (x[i].x * x[i].x + x[i].y * x[i].y) + (x[i].z * x[i].z + x[i].w * x[i].w);
  }
#pragma unroll
  for (int off = 32; off >= 1; off >>= 1) ss += __shfl_xor(ss, off, 64);
  float var = ss * (1.0f / (DDIM - 1));
  float rden = 1.0f / (sqrtf(var) + 1e-6f);
  float* orow = out + (size_t)row * DDIM;
#pragma unroll
  for (int i = 0; i < 4; ++i) {
    float4 g = *(const float4*)(gamma + lane * 4 + i * 256);
    float4 be = *(const float4*)(beta + lane * 4 + i * 256);
    float4 o;
    o.x = g.x * x[i].x * rden + be.x;
    o.y = g.y * x[i].y * rden + be.y;
    o.z = g.z * x[i].z * rden + be.z;
    o.w = g.w * x[i].w * rden + be.w;
    *(float4*)(orow + lane * 4 + i * 256) = o;
  }
}

extern "C" void kernel_launch(void* const* d_in, const int* in_sizes, int n_in,
                              void* d_out, int out_size, void* d_ws, size_t ws_size,
                              hipStream_t stream) {
  const float* query = (const float*)d_in[0];
  const float* key = (const float*)d_in[1];
  const float* value = (const float*)d_in[2];
  const int* mask = (const int*)d_in[3];  // bool passed as int32
  const float* Wq = (const float*)d_in[4];
  const float* bq = (const float*)d_in[5];
  const float* Wk = (const float*)d_in[6];
  const float* bk = (const float*)d_in[7];
  const float* Wv = (const float*)d_in[8];
  const float* bv = (const float*)d_in[9];
  const float* Wo = (const float*)d_in[10];
  const float* bo = (const float*)d_in[11];
  const float* gamma = (const float*)d_in[12];
  const float* beta = (const float*)d_in[13];
  float* out = (float*)d_out;
  char* ws = (char*)d_ws;
  const size_t MB = 1ull << 20;
  // Workspace map (64 MB):
  u64* maskbits = (u64*)(ws + 0 * MB);   // 1MB
  float* proj = (float*)(ws + 8 * MB);   // 16MB (8..24)
  u16* WT = (u16*)(ws + 24 * MB);        // 8MB: WqT,WkT,WvT,WoT contiguous
  u16* WoT = (u16*)(ws + 30 * MB);
  u16* Qp = (u16*)(ws + 32 * MB);        // Qp/Kp contiguous (8MB stride)
  u16* Kp = (u16*)(ws + 40 * MB);
  u16* VpT = (u16*)(ws + 48 * MB);       // 8MB, written directly by QKV GEMM
  u16* attnb = (u16*)(ws + 56 * MB);     // 8MB

  // merged prep: W transpose-cvt (1024 blocks) + mask bitpack (32768 blocks)
  prep_wm<<<1024 + (NB * SS * SS) / 256, 256, 0, stream>>>(Wq, Wk, Wv, Wo, WT,
                                                           mask, maskbits);
  // fused QKV projection with in-GEMM f32->bf16 A conversion;
  // V lands transposed in VpT (coalesced via LDS restage)
  gemm_bt<0><<<dim3(32, 24), 256, 0, stream>>>(query, key, value, nullptr, WT,
                                               bq, bk, bv, nullptr, Qp, VpT);
  attn_fwd<<<512, 512, 0, stream>>>(Qp, Kp, VpT, maskbits, attnb);
  // Wo projection with fused residual (x = attn@Wo + bo + query)
  gemm_bt<1><<<dim3(32, 8), 256, 0, stream>>>(nullptr, nullptr, nullptr, attnb,
                                              WoT, bo, nullptr, nullptr, query,
                                              proj, nullptr);
  ln_res<<<MROWS / 4, 256, 0, stream>>>(proj, gamma, beta, out);
}

// Round 16
// 152.959 us; speedup vs baseline: 1.1202x; 1.1202x over previous
//
#include <hip/hip_runtime.h>

// MultiHeadAttn fused pipeline for MI355X (gfx950).
// B=2, S=2048, D=1024, H=16, HD=64. Round 16: REVERT r15's in-GEMM A-cvt
// (8-way ds_write bank conflict + 2x A bytes: QKV GEMM 40->116us). Restore
// round-14 config (best: 153.2us), keep one safe piece: cvt+W-transpose
// merged into a single prep_all launch.

#define NB 2
#define SS 2048
#define DDIM 1024
#define NH 16
#define HDIM 64
#define MROWS (NB * SS)  // 4096

typedef unsigned short u16;
typedef unsigned long long u64;
typedef unsigned int u32;
typedef short bf16x8 __attribute__((ext_vector_type(8)));
typedef float f32x4 __attribute__((ext_vector_type(4)));

typedef const __attribute__((address_space(1))) void GASV;
typedef __attribute__((address_space(3))) void LASV;

__device__ __forceinline__ float dev_exp2(float x) {
  float r;
  asm("v_exp_f32 %0, %1" : "=v"(r) : "v"(x));
  return r;
}

__device__ __forceinline__ u16 f2bf(float f) {
  unsigned u = __builtin_bit_cast(unsigned, f);
  u += 0x7FFFu + ((u >> 16) & 1u);  // RNE; inputs finite
  return (u16)(u >> 16);
}

__device__ __forceinline__ u32 cvt_pk_bf16(float a, float b) {
  u32 d;  // D[15:0]=bf16(a), D[31:16]=bf16(b)
  asm("v_cvt_pk_bf16_f32 %0, %1, %2" : "=v"(d) : "v"(a), "v"(b));
  return d;
}

// ---- merged prep: q/k/v f32->bf16 (blocks 0..12287) + W transpose-cvt -----
__global__ __launch_bounds__(256) void prep_all(const float* __restrict__ q,
                                                const float* __restrict__ k,
                                                const float* __restrict__ v,
                                                u16* __restrict__ qkvb,
                                                const float* __restrict__ W0,
                                                const float* __restrict__ W1,
                                                const float* __restrict__ W2,
                                                const float* __restrict__ W3,
                                                u16* __restrict__ WTbase) {
  const int bid = blockIdx.x, tid = threadIdx.x;
  if (bid < 12288) {
    const int selq = bid >> 12;  // 0..2
    const float* in = (selq == 0) ? q : (selq == 1) ? k : v;
    size_t i = ((size_t)(bid & 4095) * 256 + tid) * 4;
    float4 val = *(const float4*)(in + i);
    uint2 o;
    o.x = cvt_pk_bf16(val.x, val.y);
    o.y = cvt_pk_bf16(val.z, val.w);
    *(uint2*)(qkvb + (size_t)selq * MROWS * DDIM + i) = o;
  } else {
    __shared__ u16 t[64][65];
    const int wb = bid - 12288;  // 0..1023
    const int z = wb >> 8;
    const float* W = (z == 0) ? W0 : (z == 1) ? W1 : (z == 2) ? W2 : W3;
    u16* WT = WTbase + (size_t)z * DDIM * DDIM;
    const int k0 = ((wb >> 4) & 15) * 64, n0 = (wb & 15) * 64;
    const int r = tid >> 4;          // 0..15
    const int c4 = (tid & 15) * 4;   // col group
#pragma unroll
    for (int it = 0; it < 4; ++it) {
      int kk = r + it * 16;
      float4 vv = *(const float4*)&W[(size_t)(k0 + kk) * DDIM + n0 + c4];
      t[c4 + 0][kk] = f2bf(vv.x);
      t[c4 + 1][kk] = f2bf(vv.y);
      t[c4 + 2][kk] = f2bf(vv.z);
      t[c4 + 3][kk] = f2bf(vv.w);
    }
    __syncthreads();
#pragma unroll
    for (int it = 0; it < 4; ++it) {
      int n = r + it * 16;
      uint2 o;
      u16* po = (u16*)&o;
#pragma unroll
      for (int j = 0; j < 4; ++j) po[j] = t[n][c4 + j];
      *(uint2*)&WT[(size_t)(n0 + n) * DDIM + k0 + c4] = o;
    }
  }
}

// ---------------- mask int32 -> bitmask (64 kv per u64 word) ----------------
__global__ __launch_bounds__(256) void cvt_mask_bits(const int* __restrict__ in,
                                                     u64* __restrict__ out) {
  size_t w = ((size_t)blockIdx.x * 256 + threadIdx.x) >> 6;
  int lane = threadIdx.x & 63;
  int v = in[w * 64 + lane];
  u64 bits = __ballot(v != 0);  // bit l = (mask[w*64+l] != 0)
  if (lane == 0) out[w] = bits;
}

// ---------------- GEMM: 128x128 tile, BK=64, 2-phase double-buffer ----------
// MODE 0: fused QKV. sel = colB0>>10: 0->Qp (scaled 0.125*log2e), 1->Kp,
//         2->V transposed via LDS restage, coalesced write to VpT[bh][d][s].
// MODE 1: Wo proj, f32 out = acc + b0[col] + resid[row][col] (residual fused).
// Col-fast XCD swizzle: each XCD owns 4 row-panels x all col-panels.
template <int MODE>
__global__ __launch_bounds__(256) void gemm_bt(const u16* __restrict__ Abase,
                                               const u16* __restrict__ BT,
                                               const float* __restrict__ b0,
                                               const float* __restrict__ b1,
                                               const float* __restrict__ b2,
                                               const float* __restrict__ resid,
                                               void* __restrict__ C,
                                               void* __restrict__ Cv) {
  __shared__ __align__(16) u16 SMEM[2][2][128][64];  // [0]=A tiles, [1]=B tiles
  u16(&Al)[2][128][64] = SMEM[0];
  u16(&Bl)[2][128][64] = SMEM[1];
  const int tid = threadIdx.x;
  const int wid = tid >> 6, lane = tid & 63;
  const int wm = (wid >> 1) * 64, wn = (wid & 1) * 64;
  const int NCOL = (MODE == 0) ? 24 : 8;
  const int lin = blockIdx.y * 32 + blockIdx.x;
  const int xcd = lin & 7, idx = lin >> 3;
  const int rowA0 = (xcd * 4 + idx / NCOL) * 128;
  const int colB0 = (idx % NCOL) * 128;
  const int sel = (MODE == 0) ? (colB0 >> 10) : 0;
  const u16* Ag = Abase + (size_t)sel * ((size_t)MROWS * DDIM) + (size_t)rowA0 * DDIM;
  const u16* Bg = BT + (size_t)colB0 * DDIM;
  f32x4 acc[4][4] = {};
  const int rl = lane >> 3;        // 0..7
  const int ce = (lane & 7) * 8;   // chunk offset (elems)

#define G_STAGE(buf, kt)                                                       \
  do {                                                                         \
    _Pragma("unroll") for (int c = 0; c < 4; ++c) {                            \
      int rt = wid * 32 + c * 8;                                               \
      __builtin_amdgcn_global_load_lds(                                        \
          (GASV*)(Ag + (size_t)(rt + rl) * DDIM + (kt) + ce),                  \
          (LASV*)((char*)&Al[buf][0][0] + rt * 128), 16, 0, 0);                \
      __builtin_amdgcn_global_load_lds(                                        \
          (GASV*)(Bg + (size_t)(rt + rl) * DDIM + (kt) + ce),                  \
          (LASV*)((char*)&Bl[buf][0][0] + rt * 128), 16, 0, 0);                \
    }                                                                          \
  } while (0)

  G_STAGE(0, 0);
  __syncthreads();
  for (int t = 0; t < 16; ++t) {  // K = 1024 = 16 * 64
    const int cur = t & 1;
    if (t < 15) G_STAGE(cur ^ 1, (t + 1) * 64);
#pragma unroll
    for (int kk = 0; kk < 64; kk += 32) {
      bf16x8 af[4], bfr[4];
#pragma unroll
      for (int i = 0; i < 4; ++i)
        af[i] = *(const bf16x8*)&Al[cur][wm + i * 16 + (lane & 15)][kk + (lane >> 4) * 8];
#pragma unroll
      for (int j = 0; j < 4; ++j)
        bfr[j] = *(const bf16x8*)&Bl[cur][wn + j * 16 + (lane & 15)][kk + (lane >> 4) * 8];
#pragma unroll
      for (int i = 0; i < 4; ++i)
#pragma unroll
        for (int j = 0; j < 4; ++j)
          acc[i][j] = __builtin_amdgcn_mfma_f32_16x16x32_bf16(af[i], bfr[j], acc[i][j], 0, 0, 0);
    }
    __syncthreads();
  }
#undef G_STAGE

  const int cb = lane & 15, hi = lane >> 4;
  if (MODE == 0) {
    if (sel == 2) {
      // V: restage transposed in LDS, then coalesced 16B/lane writes.
      u16(*T)[136] = (u16(*)[136]) & SMEM[0][0][0][0];  // 128x136 u16 = 34.8KB
      const int dcol0 = colB0 & 1023;
#pragma unroll
      for (int j = 0; j < 4; ++j) {
        int dl = wn + j * 16 + cb;  // local d 0..127
        float bv = b2[dcol0 + dl];
#pragma unroll
        for (int i = 0; i < 4; ++i) {
          int sl = wm + i * 16 + hi * 4;  // local s, 4 consecutive
          uint2 o;
          o.x = cvt_pk_bf16(acc[i][j][0] + bv, acc[i][j][1] + bv);
          o.y = cvt_pk_bf16(acc[i][j][2] + bv, acc[i][j][3] + bv);
          *(uint2*)&T[dl][sl] = o;
        }
      }
      __syncthreads();
      const int bb = rowA0 >> 11, s0 = rowA0 & (SS - 1);
#pragma unroll
      for (int it = 0; it < 8; ++it) {
        int chunk = it * 256 + tid;     // 0..2047
        int dl = chunk >> 4;            // 0..127
        int sc = (chunk & 15) * 8;      // u16 offset within row
        int dg = dcol0 + dl;
        *(bf16x8*)&((u16*)Cv)[((size_t)(bb * NH + (dg >> 6)) * HDIM + (dg & 63)) * SS +
                              s0 + sc] = *(const bf16x8*)&T[dl][sc];
      }
    } else {
      const float* bp = (sel == 0) ? b0 : b1;
      const float scale = (sel == 0) ? 0.125f * 1.44269504088896340736f : 1.0f;
      u16* dst = (u16*)C + (size_t)sel * ((size_t)MROWS * DDIM);
      const int colw0 = (colB0 & 1023) + wn;
#pragma unroll
      for (int i = 0; i < 4; ++i)
#pragma unroll
        for (int j = 0; j < 4; ++j) {
          int colw = colw0 + j * 16 + cb;
          float bv = bp[colw];
#pragma unroll
          for (int r = 0; r < 4; ++r) {
            int row = rowA0 + wm + i * 16 + hi * 4 + r;
            dst[(size_t)row * DDIM + colw] = f2bf((acc[i][j][r] + bv) * scale);
          }
        }
    }
  } else {
#pragma unroll
    for (int i = 0; i < 4; ++i)
#pragma unroll
      for (int j = 0; j < 4; ++j) {
        int col = colB0 + wn + j * 16 + cb;
        float bv = b0[col];
#pragma unroll
        for (int r = 0; r < 4; ++r) {
          int row = rowA0 + wm + i * 16 + hi * 4 + r;
          size_t off = (size_t)row * DDIM + col;
          ((float*)C)[off] = acc[i][j][r] + bv + resid[off];  // residual fused
        }
      }
  }
}

// ---------------- Flash attention (swapped QK^T, fixed-base softmax) --------
// grid: 512 blocks (XCD-swizzled). 8 waves; wave w owns q-rows [w*16,w*16+16)
// of a 128-row q-tile. Fixed m=0; masked -> exact 0 by underflow.
// 3-buffer K/V, ONE barrier/iter, counted vmcnt(2) (never drains prefetch).
__global__ __launch_bounds__(512, 4) void attn_fwd(const u16* __restrict__ Qp,
                                                   const u16* __restrict__ Kp,
                                                   const u16* __restrict__ VpT,
                                                   const u64* __restrict__ Mbits,
                                                   u16* __restrict__ O) {
  __shared__ __align__(16) u16 Kl[3][64][64];  // [buf][kv][d], swizzled
  __shared__ __align__(16) u16 Vl[3][64][64];  // [buf][d][kv], swizzled
  __shared__ __align__(16) u16 Pl[8][16][64];  // per-wave P [q][kv], swizzled
  const int tid = threadIdx.x, wid = tid >> 6, lane = tid & 63;
  const int bid = blockIdx.x;
  const int bh = (bid & 7) * 4 + ((bid >> 3) & 3);
  const int q0 = (bid >> 5) * 128;
  const int b = bh >> 4, h = bh & 15;
  const int hi = lane >> 4, cbase = lane & 15, lx = lane & 7;

  bf16x8 qf[2];
  {
    const u16* qb = Qp + (size_t)(b * SS + q0 + wid * 16 + cbase) * DDIM + h * 64 + hi * 8;
    qf[0] = *(const bf16x8*)qb;
    qf[1] = *(const bf16x8*)(qb + 32);
  }
  const bf16x8 ONES8 = {(short)0x3F80, (short)0x3F80, (short)0x3F80, (short)0x3F80,
                        (short)0x3F80, (short)0x3F80, (short)0x3F80, (short)0x3F80};
  f32x4 l_acc = (f32x4){0.f, 0.f, 0.f, 0.f};
  f32x4 accO[4];
#pragma unroll
  for (int f = 0; f < 4; ++f) accO[f] = (f32x4){0.f, 0.f, 0.f, 0.f};

  const u16* Kgb = Kp + (size_t)b * SS * DDIM + h * 64;
  const u16* Vgb = VpT + (size_t)bh * 64 * SS;
  const u64* Mb = Mbits + (size_t)(b * SS + q0 + wid * 16 + cbase) * (SS / 64);
  const int rl = lane >> 3;
  const int ceS = ((lane & 7) ^ rl) * 8;  // pre-swizzled source chunk

  // hoisted LDS fragment offsets (u16 units within one 64x64 tile)
  int fo[4][2];
#pragma unroll
  for (int f = 0; f < 4; ++f)
#pragma unroll
    for (int ks = 0; ks < 2; ++ks)
      fo[f][ks] = (f * 16 + cbase) * 64 + (((ks * 4 + hi) ^ lx) << 3);
  int pw[4];
#pragma unroll
  for (int f = 0; f < 4; ++f)
    pw[f] = cbase * 64 + (((f * 2 + (hi >> 1)) ^ lx) << 3) + ((hi & 1) << 2);
  u16* KlF = &Kl[0][0][0];
  u16* VlF = &Vl[0][0][0];
  u16* Plw = &Pl[wid][0][0];

  // 8 waves: each wave stages 8 rows of K and 8 rows of V (2 gloads/wave)
#define STAGE_KV(BUF, kv)                                                      \
  do {                                                                         \
    int rt = wid * 8;                                                          \
    __builtin_amdgcn_global_load_lds(                                          \
        (GASV*)(Kgb + (size_t)((kv) + rt + rl) * DDIM + ceS),                  \
        (LASV*)((char*)KlF + (BUF) * 8192 + rt * 128), 16, 0, 0);              \
    __builtin_amdgcn_global_load_lds(                                          \
        (GASV*)(Vgb + (size_t)(rt + rl) * SS + (kv) + ceS),                    \
        (LASV*)((char*)VlF + (BUF) * 8192 + rt * 128), 16, 0, 0);              \
  } while (0)

#define WAITVM(N) asm volatile("s_waitcnt vmcnt(" #N ")" ::: "memory")

// One iteration: counted-vmcnt wait + single barrier + prefetch t+2 + compute.
#define ATTN_ITER(T, BUF, DO_STAGE, VM)                                        \
  do {                                                                         \
    WAITVM(VM);                                                                \
    __builtin_amdgcn_s_barrier();                                              \
    u64 mrow = Mb[T];                                                          \
    if (DO_STAGE) STAGE_KV(((BUF) + 2) % 3, ((T) + 2) * 64);                   \
    f32x4 sc[4];                                                               \
    __builtin_amdgcn_s_setprio(1);                                             \
    _Pragma("unroll") for (int fn = 0; fn < 4; ++fn) {                         \
      f32x4 c = (f32x4){0.f, 0.f, 0.f, 0.f};                                   \
      _Pragma("unroll") for (int ks = 0; ks < 2; ++ks) {                       \
        bf16x8 kf = *(const bf16x8*)(KlF + (BUF) * 4096 + fo[fn][ks]);         \
        c = __builtin_amdgcn_mfma_f32_16x16x32_bf16(kf, qf[ks], c, 0, 0, 0);   \
      }                                                                        \
      sc[fn] = c;                                                              \
    }                                                                          \
    __builtin_amdgcn_s_setprio(0);                                             \
    /* p = exp2(s - 512*maskbit), fixed base m=0; masked -> exact 0 */         \
    u64 mh = mrow >> (hi * 4);                                                 \
    u32 mlo = (u32)mh, mhi2 = (u32)(mh >> 32);                                 \
    _Pragma("unroll") for (int fn = 0; fn < 4; ++fn) {                         \
      u32 b4 = ((fn < 2) ? mlo : mhi2) >> ((fn & 1) * 16);                     \
      _Pragma("unroll") for (int j = 0; j < 4; ++j) {                          \
        float bf_ = (float)((b4 >> j) & 1u);                                   \
        sc[fn][j] = dev_exp2(fmaf(bf_, -512.f, sc[fn][j]));                    \
      }                                                                        \
    }                                                                          \
    _Pragma("unroll") for (int fn = 0; fn < 4; ++fn) {                         \
      uint2 wpair;                                                             \
      wpair.x = cvt_pk_bf16(sc[fn][0], sc[fn][1]);                             \
      wpair.y = cvt_pk_bf16(sc[fn][2], sc[fn][3]);                             \
      *(uint2*)(Plw + pw[fn]) = wpair;                                         \
    }                                                                          \
    bf16x8 pf0 = *(const bf16x8*)(Plw + fo[0][0]);                             \
    bf16x8 pf1 = *(const bf16x8*)(Plw + fo[0][1]);                             \
    __builtin_amdgcn_s_setprio(1);                                             \
    l_acc = __builtin_amdgcn_mfma_f32_16x16x32_bf16(pf0, ONES8, l_acc, 0, 0, 0); \
    l_acc = __builtin_amdgcn_mfma_f32_16x16x32_bf16(pf1, ONES8, l_acc, 0, 0, 0); \
    _Pragma("unroll") for (int nd = 0; nd < 4; ++nd) {                         \
      bf16x8 v0 = *(const bf16x8*)(VlF + (BUF) * 4096 + fo[nd][0]);            \
      bf16x8 v1 = *(const bf16x8*)(VlF + (BUF) * 4096 + fo[nd][1]);            \
      accO[nd] = __builtin_amdgcn_mfma_f32_16x16x32_bf16(pf0, v0, accO[nd], 0, 0, 0); \
      accO[nd] = __builtin_amdgcn_mfma_f32_16x16x32_bf16(pf1, v1, accO[nd], 0, 0, 0); \
    }                                                                          \
    __builtin_amdgcn_s_setprio(0);                                             \
  } while (0)

  // prologue: two tiles in flight
  STAGE_KV(0, 0);
  STAGE_KV(1, 64);
  // main loop: 30 iters in x3 unroll (compile-time buffer index), vmcnt(2)
  for (int t3 = 0; t3 < 30; t3 += 3) {
    ATTN_ITER(t3 + 0, 0, true, 2);
    ATTN_ITER(t3 + 1, 1, true, 2);
    ATTN_ITER(t3 + 2, 2, true, 2);
  }
  // tail: t=30 (buf 0, no stage), t=31 (buf 1, full drain)
  ATTN_ITER(30, 0, false, 2);
  ATTN_ITER(31, 1, false, 0);
#undef ATTN_ITER
#undef WAITVM
#undef STAGE_KV

  // l_acc[j] = sum_kv P[q=hi*4+j][kv] (all columns of the ones-MFMA equal)
#pragma unroll
  for (int nd = 0; nd < 4; ++nd)
#pragma unroll
    for (int j = 0; j < 4; ++j) {
      int row = q0 + wid * 16 + hi * 4 + j;
      int col = h * 64 + nd * 16 + cbase;
      O[(size_t)(b * SS + row) * DDIM + col] = f2bf(accO[nd][j] / l_acc[j]);
    }
}

// ---------------- LayerNorm on x (residual already added) -------------------
// wave-per-row: 4 rows/block, pure shfl reduction, no LDS/barriers.
__global__ __launch_bounds__(256) void ln_res(const float* __restrict__ xin,
                                              const float* __restrict__ gamma,
                                              const float* __restrict__ beta,
                                              float* __restrict__ out) {
  const int tid = threadIdx.x, wid = tid >> 6, lane = tid & 63;
  const int row = blockIdx.x * 4 + wid;
  const float* xr = xin + (size_t)row * DDIM;
  float4 x[4];
  float s = 0.f;
#pragma unroll
  for (int i = 0; i < 4; ++i) {
    x[i] = *(const float4*)(xr + lane * 4 + i * 256);
    s += (x[i].x + x[i].y) + (x[i].z + x[i].w);
  }
#pragma unroll
  for (int off = 32; off >= 1; off >>= 1) s += __shfl_xor(s, off, 64);
  float mean = s * (1.0f / DDIM);
  float ss = 0.f;
#pragma unroll
  for (int i = 0; i < 4; ++i) {
    x[i].x -= mean; x[i].y -= mean; x[i].z -= mean; x[i].w -= mean;
    ss += (x[i].x * x[i].x + x[i].y * x[i].y) + (x[i].z * x[i].z + x[i].w * x[i].w);
  }
#pragma unroll
  for (int off = 32; off >= 1; off >>= 1) ss += __shfl_xor(ss, off, 64);
  float var = ss * (1.0f / (DDIM - 1));
  float rden = 1.0f / (sqrtf(var) + 1e-6f);
  float* orow = out + (size_t)row * DDIM;
#pragma unroll
  for (int i = 0; i < 4; ++i) {
    float4 g = *(const float4*)(gamma + lane * 4 + i * 256);
    float4 be = *(const float4*)(beta + lane * 4 + i * 256);
    float4 o;
    o.x = g.x * x[i].x * rden + be.x;
    o.y = g.y * x[i].y * rden + be.y;
    o.z = g.z * x[i].z * rden + be.z;
    o.w = g.w * x[i].w * rden + be.w;
    *(float4*)(orow + lane * 4 + i * 256) = o;
  }
}

extern "C" void kernel_launch(void* const* d_in, const int* in_sizes, int n_in,
                              void* d_out, int out_size, void* d_ws, size_t ws_size,
                              hipStream_t stream) {
  const float* query = (const float*)d_in[0];
  const float* key = (const float*)d_in[1];
  const float* value = (const float*)d_in[2];
  const int* mask = (const int*)d_in[3];  // bool passed as int32
  const float* Wq = (const float*)d_in[4];
  const float* bq = (const float*)d_in[5];
  const float* Wk = (const float*)d_in[6];
  const float* bk = (const float*)d_in[7];
  const float* Wv = (const float*)d_in[8];
  const float* bv = (const float*)d_in[9];
  const float* Wo = (const float*)d_in[10];
  const float* bo = (const float*)d_in[11];
  const float* gamma = (const float*)d_in[12];
  const float* beta = (const float*)d_in[13];
  float* out = (float*)d_out;
  char* ws = (char*)d_ws;
  const size_t MB = 1ull << 20;
  // Workspace map (64 MB):
  u16* qkvb = (u16*)(ws + 0 * MB);  // 24MB qb/kb/vb contiguous
  u16* WT = (u16*)(ws + 24 * MB);   // 8MB: WqT,WkT,WvT,WoT contiguous
  u16* WoT = (u16*)(ws + 30 * MB);
  u16* Qp = (u16*)(ws + 32 * MB);   // Qp/Kp contiguous (8MB stride)
  u16* Kp = (u16*)(ws + 40 * MB);
  u16* VpT = (u16*)(ws + 48 * MB);  // 8MB, written directly by QKV GEMM
  u16* attnb = (u16*)(ws + 56 * MB); // 8MB
  u64* maskbits = (u64*)(ws + 0 * MB);   // 1MB over qb (dead after QKV-GEMM)
  float* proj = (float*)(ws + 8 * MB);   // 16MB over kb+vb (dead after QKV-GEMM)

  // merged prep: qkv f32->bf16 (12288 blocks) + W transpose-cvt (1024 blocks)
  prep_all<<<12288 + 1024, 256, 0, stream>>>(query, key, value, qkvb,
                                             Wq, Wk, Wv, Wo, WT);
  // fused QKV projection; V lands transposed in VpT (coalesced via LDS restage)
  gemm_bt<0><<<dim3(32, 24), 256, 0, stream>>>(qkvb, WT, bq, bk, bv, nullptr, Qp, VpT);
  // mask bitpack after QKV-GEMM (qb region dead)
  cvt_mask_bits<<<(NB * SS * SS) / 256, 256, 0, stream>>>(mask, maskbits);
  attn_fwd<<<512, 512, 0, stream>>>(Qp, Kp, VpT, maskbits, attnb);
  // Wo projection with fused residual (x = attn@Wo + bo + query)
  gemm_bt<1><<<dim3(32, 8), 256, 0, stream>>>(attnb, WoT, bo, nullptr, nullptr,
                                              query, proj, nullptr);
  ln_res<<<MROWS / 4, 256, 0, stream>>>(proj, gamma, beta, out);
}